// Round 18
// baseline (1415.339 us; speedup 1.0000x reference)
//
#include <hip/hip_runtime.h>
#include <math.h>
#include <float.h>

// DGCNN forward, MI355X.
// kNN: 3-term split-bf16 MFMA approx distances (xx folded into GEMM) ->
//      packed-key top-10 per partition -> exact f32 re-rank (r2 rounding).
// Edge u/v GEMMs: 6-term split-bf16 MFMA (error ~1e-9 rel = f32 class).
// pack_layer: ONE pass emits xxg + kNN packs + xpm + 6-term GEMM pack.
// pack6_w_all: all 4 layers' weights packed in one dispatch.
// Edge stats: non-atomic partials; finalize = 1 wave/channel double reduce.
// Fusion: z=2, 4 accs/wave; bf16 h + sign-selected f32 extrema; stats sweep.
// r18: L4 kNN z-split 2->4 (isolated re-test of r11's config).

#define LEAKY(y) ((y) >= 0.f ? (y) : 0.2f * (y))

using f32x16 = __attribute__((ext_vector_type(16))) float;
using bf16x8 = __attribute__((ext_vector_type(8))) __bf16;
using short8v = __attribute__((ext_vector_type(8))) short;

__device__ inline ushort f2bf(float x) {
  unsigned u = __float_as_uint(x);
  unsigned r = (u + 0x7fff + ((u >> 16) & 1)) >> 16;
  return (ushort)r;
}

// ---- merged per-layer pack: xx + kNN 3-term packs + xpm + 6-term GEMM pack -
template<int C, int KCc, int KCX>
__global__ __launch_bounds__(256) void pack_layer(const float* __restrict__ xin, long bstride,
                                                  int N, float* __restrict__ xxg,
                                                  ushort* __restrict__ packR,
                                                  ushort* __restrict__ packC,
                                                  float* __restrict__ xpm,
                                                  ushort* __restrict__ packX6) {
  __shared__ float xt[C][32];
  __shared__ float sxx[32];
  const int tid = threadIdx.x;
  const int pb = blockIdx.x, b = blockIdx.y;
  for (int i = tid; i < C * 32; i += 256) {
    int c = i >> 5, j = i & 31;
    xt[c][j] = xin[(long)b * bstride + (long)c * N + pb * 32 + j];
  }
  __syncthreads();
  if (tid < 32) {
    float s = 0.f;
    for (int c = 0; c < C; ++c) { float t = xt[c][tid]; s += t * t; }
    sxx[tid] = s;
    xxg[(long)b * N + pb * 32 + tid] = s;
  }
  __syncthreads();
  for (int i = tid; i < 32 * C; i += 256) {
    int pt = i / C, c = i % C;
    xpm[((long)b * N + pb * 32 + pt) * C + c] = xt[c][pt];
  }
  const int PB = N >> 5;
  for (int it = tid; it < KCc * 64; it += 256) {
    int kc = it >> 6, l = it & 63;
    int pt = l & 31;
    union { ushort u[8]; short8v v; } R, Cc;
    #pragma unroll
    for (int e = 0; e < 8; ++e) {
      int kp = kc * 16 + ((l >> 5) << 3) + e;
      ushort rv = 0, cv = 0;
      if (kp < 3 * C) {
        int s = kp / C, c = kp % C;
        float xv = xt[c][pt];
        ushort hi = f2bf(xv);
        float hif = __uint_as_float((unsigned)hi << 16);
        ushort mid = f2bf(xv - hif);
        rv = (s == 2) ? mid : hi;
        cv = (s == 1) ? mid : hi;
      } else if (kp == 3 * C) {
        float xxv = sxx[pt];
        cv = f2bf(xxv);
        rv = 0xBF00;                       // bf16(-0.5), exact
      } else if (kp == 3 * C + 1) {
        float xxv = sxx[pt];
        ushort hi = f2bf(xxv);
        float hif = __uint_as_float((unsigned)hi << 16);
        cv = f2bf(xxv - hif);
        rv = 0xBF00;
      }
      R.u[e] = rv; Cc.u[e] = cv;
    }
    long off = (((long)b * PB + pb) * KCc + kc) * 512 + l * 8;
    *reinterpret_cast<short8v*>(&packR[off]) = R.v;
    *reinterpret_cast<short8v*>(&packC[off]) = Cc.v;
  }
  for (int it = tid; it < KCX * 64; it += 256) {
    int kc = it >> 6, l = it & 63;
    int pt = l & 31;
    union { ushort u[8]; short8v v; } P;
    #pragma unroll
    for (int e = 0; e < 8; ++e) {
      int kp = kc * 16 + ((l >> 5) << 3) + e;
      ushort val = 0;
      if (kp < 6 * C) {
        int s = kp / C, c = kp % C;
        float xv = xt[c][pt];
        ushort hi = f2bf(xv);
        float hif = __uint_as_float((unsigned)hi << 16);
        float r1 = xv - hif;
        ushort mid = f2bf(r1);
        float midf = __uint_as_float((unsigned)mid << 16);
        ushort lo = f2bf(r1 - midf);
        val = (s == 1 || s == 3) ? mid : ((s == 4) ? lo : hi);
      }
      P.u[e] = val;
    }
    long off = (((long)b * PB + pb) * KCX + kc) * 512 + l * 8;
    *reinterpret_cast<short8v*>(&packX6[off]) = P.v;
  }
}

// ----------------------------------------------------- kNN phase 1 (MFMA) ---
#define KNN_SCAN(SELF)                                            \
  _Pragma("unroll")                                               \
  for (int reg = 0; reg < 16; ++reg) {                            \
    int m_loc = (reg & 3) + 8 * (reg >> 2) + 4 * hf;              \
    float d = fmaf(-2.0f, acc[reg], xr);                          \
    d = fmaxf(d, 0.f);                                            \
    unsigned key = (__float_as_uint(d) & KEYMASK) |               \
                   (unsigned)((t << 5) | m_loc);                  \
    if (SELF && ((mb << 5) | m_loc) == n_glob) key = 0xFFFFFFFFu; \
    if (key < tk[9]) {                                            \
      unsigned kc = key;                                          \
      _Pragma("unroll")                                           \
      for (int s_ = 0; s_ < 10; ++s_) {                           \
        unsigned mn_ = min(kc, tk[s_]);                           \
        kc = max(kc, tk[s_]);                                     \
        tk[s_] = mn_;                                             \
      }                                                           \
    }                                                             \
  }

template<int KCc, int MINW, int Z>
__global__ __launch_bounds__(256, MINW) void knn_v5(const ushort* __restrict__ packR,
                                                    const ushort* __restrict__ packC,
                                                    const float* __restrict__ xxg,
                                                    int N, int* __restrict__ cand) {
  constexpr int SA_ELEMS = KCc * 512;
  constexpr int SA_BYTES = SA_ELEMS * 2;
  constexpr int POOL = (2 * SA_BYTES > 10240) ? 2 * SA_BYTES : 10240;
  __shared__ __align__(16) char smem[POOL];
  ushort* const sA0 = (ushort*)smem;
  ushort* const sA1 = (ushort*)(smem + SA_BYTES);

  const int tid = threadIdx.x;
  const int b = blockIdx.y, rowblk = blockIdx.x, z = blockIdx.z;
  const int w = tid >> 6, l = tid & 63;
  const int lane31 = l & 31, hf = l >> 5;
  const int PB = N >> 5;
  const int HALF = PB / Z;
  const unsigned IDXMASK = (unsigned)(HALF * 32 - 1);
  const unsigned KEYMASK = ~IDXMASK;
  const int myblk = rowblk * 4 + w;

  const ushort* rp = packR + (((long)b * PB + myblk) * (long)KCc) * 512 + l * 8;
  bf16x8 bfr[KCc];
  #pragma unroll
  for (int kc = 0; kc < KCc; ++kc)
    bfr[kc] = *reinterpret_cast<const bf16x8*>(rp + kc * 512);

  const ushort* srcb = packC + ((long)b * PB) * (long)SA_ELEMS;
  const int mb0 = z * HALF;

  {
    const ushort* src = srcb + (long)mb0 * SA_ELEMS;
    for (int i = tid * 8; i < SA_ELEMS; i += 2048)
      __builtin_amdgcn_global_load_lds(
          (const __attribute__((address_space(1))) void*)(src + i),
          (__attribute__((address_space(3))) void*)(sA0 + i), 16, 0, 0);
  }

  const int n_glob = rowblk * 128 + w * 32 + lane31;
  const float xr = xxg[(long)b * N + n_glob];

  unsigned tk[10];
  #pragma unroll
  for (int s = 0; s < 10; ++s) tk[s] = 0xFFFFFFFFu;

  __syncthreads();

  for (int t = 0; t < HALF; ++t) {
    const int mb = mb0 + t;
    const ushort* curA = (t & 1) ? sA1 : sA0;
    ushort* nxtA = (t & 1) ? sA0 : sA1;
    if (t + 1 < HALF) {
      const ushort* src = srcb + (long)(mb + 1) * SA_ELEMS;
      for (int i = tid * 8; i < SA_ELEMS; i += 2048)
        __builtin_amdgcn_global_load_lds(
            (const __attribute__((address_space(1))) void*)(src + i),
            (__attribute__((address_space(3))) void*)(nxtA + i), 16, 0, 0);
    }
    f32x16 acc = {};
    #pragma unroll
    for (int kc = 0; kc < KCc; ++kc) {
      bf16x8 af = *reinterpret_cast<const bf16x8*>(curA + kc * 512 + l * 8);
      acc = __builtin_amdgcn_mfma_f32_32x32x16_bf16(af, bfr[kc], acc, 0, 0, 0);
    }
    if (mb == myblk) {
      KNN_SCAN(true)
    } else {
      KNN_SCAN(false)
    }
    __syncthreads();
  }

  unsigned* mK = (unsigned*)smem;
  const int row = w * 32 + lane31;
  #pragma unroll
  for (int s = 0; s < 10; ++s)
    mK[row * 20 + hf * 10 + s] = tk[s];
  __syncthreads();
  if (tid < 128) {
    int p0 = 0, p1 = 0;
    const long ob = ((long)b * N + rowblk * 128 + tid) * (Z * 10) + z * 10;
    const int base_m = z * HALF * 32;
    for (int s = 0; s < 10; ++s) {
      unsigned k0 = mK[tid * 20 + p0];
      unsigned k1 = mK[tid * 20 + 10 + p1];
      bool t0 = k0 < k1;
      unsigned kk = t0 ? k0 : k1;
      cand[ob + s] = base_m + (int)(kk & IDXMASK);
      if (t0) ++p0; else ++p1;
    }
  }
}

// ---------------- exact f32 re-rank of P candidates (point-major input) -----
template<int C, int P>
__global__ __launch_bounds__(320) void rerank_kernel(const float* __restrict__ xpm,
                                                     int N, const float* __restrict__ xxg,
                                                     const int* __restrict__ cand,
                                                     int* __restrict__ idx_out) {
  constexpr int ROWS = 320 / P;
  __shared__ float sq[ROWS][C];
  __shared__ float sd[ROWS][P + 1];
  __shared__ int   si[ROWS][P + 1];
  const int tid = threadIdx.x;
  const int b = blockIdx.y, n0 = blockIdx.x * ROWS;
  const float* xb = xpm + (long)b * N * C;
  for (int i = tid; i < ROWS * C; i += 320) {
    int r = i / C, c = i % C;
    sq[r][c] = xb[(long)(n0 + r) * C + c];
  }
  __syncthreads();
  const int r = tid / P, j = tid % P;
  const int n = n0 + r;
  const int m = cand[((long)b * N + n) * P + j];
  const float* cv = xb + (long)m * C;
  float dot = 0.f;
  if constexpr ((C & 3) == 0) {
    for (int c = 0; c < C; c += 4) {
      float4 v4 = *reinterpret_cast<const float4*>(cv + c);
      dot = fmaf(sq[r][c + 0], v4.x, dot);
      dot = fmaf(sq[r][c + 1], v4.y, dot);
      dot = fmaf(sq[r][c + 2], v4.z, dot);
      dot = fmaf(sq[r][c + 3], v4.w, dot);
    }
  } else {
    for (int c = 0; c < C; ++c) dot = fmaf(sq[r][c], cv[c], dot);
  }
  float d = (xxg[(long)b * N + n] - 2.0f * dot) + xxg[(long)b * N + m];
  if (m == n) d = 3.0e38f;
  sd[r][j] = d; si[r][j] = m;
  __syncthreads();
  int rank = 0;
  #pragma unroll
  for (int t = 0; t < P; ++t) {
    float dd = sd[r][t]; int ii = si[r][t];
    if (dd < d || (dd == d && ii < m)) rank++;
  }
  if (rank < 9) idx_out[((long)b * N + n) * 9 + rank] = m;
}

// ---------------- ALL edge weight packs in one dispatch (6-term split) ------
__global__ __launch_bounds__(256) void pack6_w_all(const float* __restrict__ w1,
                                                   const float* __restrict__ w2,
                                                   const float* __restrict__ w3,
                                                   const float* __restrict__ w4,
                                                   ushort* __restrict__ packAw) {
  __shared__ float wt[32][129];
  const int mo = blockIdx.x;
  const int tid = threadIdx.x;
  int C, NOB, moL; long base; const float* W;
  if (mo < 4)       { C = 3;   NOB = 2; moL = mo;      base = 0;               W = w1; }
  else if (mo < 8)  { C = 64;  NOB = 2; moL = mo - 4;  base = 4096;            W = w2; }
  else if (mo < 16) { C = 64;  NOB = 4; moL = mo - 8;  base = 53248;           W = w3; }
  else              { C = 128; NOB = 8; moL = mo - 16; base = 151552;          W = w4; }
  const int KCW = (6 * C + 15) / 16;
  const int mat = moL / NOB, ob = moL % NOB;
  for (int i = tid; i < 32 * C; i += 256) {
    int o = i / C, c = i % C;
    float w1v = W[(long)(ob * 32 + o) * 2 * C + c];
    float w2v = W[(long)(ob * 32 + o) * 2 * C + C + c];
    wt[o][c] = mat ? w2v : (w1v - w2v);
  }
  __syncthreads();
  ushort* dst = packAw + base + (long)moL * KCW * 512;
  for (int it = tid; it < KCW * 64; it += 256) {
    int kc = it >> 6, l = it & 63;
    union { ushort u[8]; short8v v; } P;
    #pragma unroll
    for (int e = 0; e < 8; ++e) {
      int kp = kc * 16 + ((l >> 5) << 3) + e;
      ushort val = 0;
      if (kp < 6 * C) {
        int s = kp / C, c = kp % C;
        float xv = wt[l & 31][c];
        ushort hi = f2bf(xv);
        float hif = __uint_as_float((unsigned)hi << 16);
        float r1 = xv - hif;
        ushort mid = f2bf(r1);
        float midf = __uint_as_float((unsigned)mid << 16);
        ushort lo = f2bf(r1 - midf);
        val = (s == 2 || s == 3) ? mid : ((s == 5) ? lo : hi);
      }
      P.u[e] = val;
    }
    *reinterpret_cast<short8v*>(&dst[((long)kc) * 512 + l * 8]) = P.v;
  }
}

// ------------- edge u,v GEMM on MFMA: D[o][n] = sum W'[o][k'] X[n][k'] ------
template<int KCW, int NOB>
__global__ __launch_bounds__(256) void edge_gemm6(const ushort* __restrict__ packX,
                                                  const ushort* __restrict__ packAw,
                                                  int N,
                                                  float* __restrict__ u,
                                                  float* __restrict__ v) {
  constexpr int NT = 2 * NOB;
  constexpr int TPW = NT / 4;
  constexpr int O = NOB * 32;
  const int nb = blockIdx.x, b = blockIdx.y;
  const int w = threadIdx.x >> 6, l = threadIdx.x & 63;
  const int lane31 = l & 31, hf = l >> 5;
  const ushort* xp = packX + ((long)(b * (N >> 5) + nb) * KCW) * 512 + l * 8;

  f32x16 acc[TPW] = {};
  const ushort* aptr[TPW];
  #pragma unroll
  for (int ti = 0; ti < TPW; ++ti) {
    int t = w + ti * 4;
    int mat = t & 1, ob = t >> 1;
    aptr[ti] = packAw + ((long)(mat * NOB + ob) * KCW) * 512 + l * 8;
  }

  for (int kc = 0; kc < KCW; ++kc) {
    bf16x8 bf = *reinterpret_cast<const bf16x8*>(xp + (long)kc * 512);
    #pragma unroll
    for (int ti = 0; ti < TPW; ++ti) {
      bf16x8 af = *reinterpret_cast<const bf16x8*>(aptr[ti] + (long)kc * 512);
      acc[ti] = __builtin_amdgcn_mfma_f32_32x32x16_bf16(af, bf, acc[ti], 0, 0, 0);
    }
  }

  #pragma unroll
  for (int ti = 0; ti < TPW; ++ti) {
    int t = w + ti * 4;
    int mat = t & 1, ob = t >> 1;
    float* dst = mat ? v : u;
    long rowbase = ((long)b * N + nb * 32 + lane31) * O + ob * 32;
    #pragma unroll
    for (int q = 0; q < 4; ++q) {
      float4 st = make_float4(acc[ti][4 * q + 0], acc[ti][4 * q + 1],
                              acc[ti][4 * q + 2], acc[ti][4 * q + 3]);
      *reinterpret_cast<float4*>(&dst[rowbase + 4 * hf + 8 * q]) = st;
    }
  }
}

// -------- gather pass: stats partials + sign-selected extremum hsel ---------
__global__ __launch_bounds__(256) void edge_pass(const float* __restrict__ u,
                                                 const float* __restrict__ v,
                                                 const int* __restrict__ idx,
                                                 const float* __restrict__ g,
                                                 int O, int N,
                                                 float* __restrict__ hsel,
                                                 float* __restrict__ part1,
                                                 float* __restrict__ part2) {
  const int tid = threadIdx.x;
  const int n0 = blockIdx.x * 64, o0 = blockIdx.y * 64, b = blockIdx.z;
  __shared__ int sidx[64][9];
  __shared__ float4 redA[4][16];
  __shared__ float4 redB[4][16];
  for (int i = tid; i < 576; i += 256)
    ((int*)sidx)[i] = idx[((long)b * N + n0) * 9 + i];
  __syncthreads();
  const int nl = tid >> 4, oq = tid & 15;
  const long base = (long)b * N;
  const int ocol = o0 + 4 * oq;
  const float4 gv = *reinterpret_cast<const float4*>(&g[ocol]);
  float4 s1 = make_float4(0.f, 0.f, 0.f, 0.f);
  float4 s2 = make_float4(0.f, 0.f, 0.f, 0.f);
  for (int gg = 0; gg < 4; ++gg) {
    const int n = gg * 16 + nl;
    const float4 u4 = *reinterpret_cast<const float4*>(&u[(base + n0 + n) * O + ocol]);
    float4 mx = make_float4(-3.0e38f, -3.0e38f, -3.0e38f, -3.0e38f);
    float4 mn = make_float4(3.0e38f, 3.0e38f, 3.0e38f, 3.0e38f);
    #pragma unroll
    for (int k = 0; k < 9; ++k) {
      int m = sidx[n][k];
      const float4 v4 = *reinterpret_cast<const float4*>(&v[(base + m) * O + ocol]);
      float hx = u4.x + v4.x, hy = u4.y + v4.y, hz = u4.z + v4.z, hw = u4.w + v4.w;
      s1.x += hx; s1.y += hy; s1.z += hz; s1.w += hw;
      s2.x = fmaf(hx, hx, s2.x); s2.y = fmaf(hy, hy, s2.y);
      s2.z = fmaf(hz, hz, s2.z); s2.w = fmaf(hw, hw, s2.w);
      mx.x = fmaxf(mx.x, hx); mx.y = fmaxf(mx.y, hy); mx.z = fmaxf(mx.z, hz); mx.w = fmaxf(mx.w, hw);
      mn.x = fminf(mn.x, hx); mn.y = fminf(mn.y, hy); mn.z = fminf(mn.z, hz); mn.w = fminf(mn.w, hw);
    }
    float4 sel;
    sel.x = (gv.x >= 0.f) ? mx.x : mn.x;
    sel.y = (gv.y >= 0.f) ? mx.y : mn.y;
    sel.z = (gv.z >= 0.f) ? mx.z : mn.z;
    sel.w = (gv.w >= 0.f) ? mx.w : mn.w;
    *reinterpret_cast<float4*>(&hsel[(base + n0 + n) * O + ocol]) = sel;
  }
  s1.x += __shfl_xor(s1.x, 16); s1.y += __shfl_xor(s1.y, 16);
  s1.z += __shfl_xor(s1.z, 16); s1.w += __shfl_xor(s1.w, 16);
  s2.x += __shfl_xor(s2.x, 16); s2.y += __shfl_xor(s2.y, 16);
  s2.z += __shfl_xor(s2.z, 16); s2.w += __shfl_xor(s2.w, 16);
  s1.x += __shfl_xor(s1.x, 32); s1.y += __shfl_xor(s1.y, 32);
  s1.z += __shfl_xor(s1.z, 32); s1.w += __shfl_xor(s1.w, 32);
  s2.x += __shfl_xor(s2.x, 32); s2.y += __shfl_xor(s2.y, 32);
  s2.z += __shfl_xor(s2.z, 32); s2.w += __shfl_xor(s2.w, 32);
  if ((tid & 48) == 0) { redA[tid >> 6][oq] = s1; redB[tid >> 6][oq] = s2; }
  __syncthreads();
  if (tid < 16) {
    float4 a = redA[0][tid], bb = redB[0][tid];
    #pragma unroll
    for (int ww = 1; ww < 4; ++ww) {
      float4 t1 = redA[ww][tid], t2 = redB[ww][tid];
      a.x += t1.x; a.y += t1.y; a.z += t1.z; a.w += t1.w;
      bb.x += t2.x; bb.y += t2.y; bb.z += t2.z; bb.w += t2.w;
    }
    int o = o0 + 4 * tid;
    int part = b * gridDim.x + blockIdx.x;
    part1[(long)(o + 0) * 512 + part] = a.x;  part2[(long)(o + 0) * 512 + part] = bb.x;
    part1[(long)(o + 1) * 512 + part] = a.y;  part2[(long)(o + 1) * 512 + part] = bb.y;
    part1[(long)(o + 2) * 512 + part] = a.z;  part2[(long)(o + 2) * 512 + part] = bb.z;
    part1[(long)(o + 3) * 512 + part] = a.w;  part2[(long)(o + 3) * 512 + part] = bb.w;
  }
}

// -------- finalize: one wave per channel, double shuffle reduce -------------
__global__ __launch_bounds__(256) void finalize_scale(const float* __restrict__ part1,
                                                      const float* __restrict__ part2,
                                                      const float* __restrict__ g,
                                                      const float* __restrict__ beta,
                                                      double invM, int O,
                                                      float* __restrict__ scale,
                                                      float* __restrict__ shift) {
  int o = (blockIdx.x * 256 + threadIdx.x) >> 6;   // one wave per channel
  int lane = threadIdx.x & 63;
  if (o >= O) return;
  double s1 = 0.0, s2 = 0.0;
  #pragma unroll
  for (int j = 0; j < 8; ++j) {
    int k = j * 64 + lane;
    s1 += (double)part1[(long)o * 512 + k];
    s2 += (double)part2[(long)o * 512 + k];
  }
  #pragma unroll
  for (int off = 1; off < 64; off <<= 1) {
    s1 += __shfl_xor(s1, off);
    s2 += __shfl_xor(s2, off);
  }
  if (lane == 0) {
    double mean = s1 * invM;
    double var = s2 * invM - mean * mean;
    double sc = (double)g[o] / sqrt(var + 1e-5);
    scale[o] = (float)sc;
    shift[o] = (float)((double)beta[o] - mean * sc);
  }
}

// ------------------- elementwise finalize + transpose to (B,O,N) ------------
__global__ __launch_bounds__(256) void edge_out(const float* __restrict__ hsel,
                                                const float* __restrict__ scale,
                                                const float* __restrict__ shift,
                                                int O, int N,
                                                float* __restrict__ outp, long out_bstride) {
  const int tid = threadIdx.x;
  const int b = blockIdx.y, n0 = blockIdx.x * 64;
  __shared__ float yt[64][65];
  const int ol = tid & 63, nl = tid >> 6;
  const long base = (long)b * N;
  for (int oc = 0; oc < O; oc += 64) {
    float sc = scale[oc + ol], sh = shift[oc + ol];
    __syncthreads();
    for (int ng = 0; ng < 16; ++ng) {
      int n = ng * 4 + nl;
      float hv = hsel[(base + n0 + n) * O + oc + ol];
      float y = sc * hv + sh;
      yt[ol][n] = LEAKY(y);
    }
    __syncthreads();
    for (int rr = 0; rr < 16; ++rr) {
      int r = rr * 4 + nl;
      outp[(long)b * out_bstride + (long)(oc + r) * N + n0 + ol] = yt[r][ol];
    }
  }
}

// ----------------- fusion packs: weights (A-pattern), feat (B-pattern) ------
__global__ __launch_bounds__(256) void pack3_wf(const float* __restrict__ wf,
                                                ushort* __restrict__ packW) {
  __shared__ float wt[32][129];
  const int po = blockIdx.x;
  const int tid = threadIdx.x;
  for (int c0 = 0; c0 < 512; c0 += 128) {
    __syncthreads();
    for (int i = tid; i < 32 * 128; i += 256) {
      int o = i >> 7, c = i & 127;
      wt[o][c] = wf[(long)(po * 32 + o) * 512 + c0 + c];
    }
    __syncthreads();
    #pragma unroll
    for (int s = 0; s < 3; ++s) {
      int kc0 = (s * 512 + c0) >> 4;
      for (int it = tid; it < 8 * 64; it += 256) {
        int kcl = it >> 6, l = it & 63;
        union { ushort u[8]; short8v v; } P;
        #pragma unroll
        for (int e = 0; e < 8; ++e) {
          int kp = (kc0 + kcl) * 16 + ((l >> 5) << 3) + e;
          int c = kp - s * 512 - c0;
          float xv = wt[l & 31][c];
          ushort hi = f2bf(xv);
          if (s == 1) {
            float hif = __uint_as_float((unsigned)hi << 16);
            P.u[e] = f2bf(xv - hif);
          } else P.u[e] = hi;
        }
        *reinterpret_cast<short8v*>(&packW[((long)po * 96 + kc0 + kcl) * 512 + l * 8]) = P.v;
      }
    }
  }
}

__global__ __launch_bounds__(256) void pack3_feat(const float* __restrict__ feat, int N,
                                                  ushort* __restrict__ packB) {
  __shared__ float xt[64][33];
  const int pb = blockIdx.x, b = blockIdx.y;
  const int tid = threadIdx.x;
  const int PB = N >> 5;
  for (int c0 = 0; c0 < 512; c0 += 64) {
    __syncthreads();
    for (int i = tid; i < 64 * 32; i += 256) {
      int c = i >> 5, j = i & 31;
      xt[c][j] = feat[((long)b * 512 + c0 + c) * N + pb * 32 + j];
    }
    __syncthreads();
    #pragma unroll
    for (int s = 0; s < 3; ++s) {
      int kc0 = (s * 512 + c0) >> 4;
      for (int it = tid; it < 4 * 64; it += 256) {
        int kcl = it >> 6, l = it & 63;
        union { ushort u[8]; short8v v; } P;
        #pragma unroll
        for (int e = 0; e < 8; ++e) {
          int kp = (kc0 + kcl) * 16 + ((l >> 5) << 3) + e;
          int c = kp - s * 512 - c0;
          float xv = xt[c][l & 31];
          ushort hi = f2bf(xv);
          if (s == 2) {
            float hif = __uint_as_float((unsigned)hi << 16);
            P.u[e] = f2bf(xv - hif);
          } else P.u[e] = hi;
        }
        *reinterpret_cast<short8v*>(
            &packB[(((long)b * PB + pb) * 96 + kc0 + kcl) * 512 + l * 8]) = P.v;
      }
    }
  }
}

// --- fusion MFMA: z=2, 4 accs/wave; bf16 h + sign-selected extremum ---------
#define FUS_EPI(ACC, Q)                                                          \
  _Pragma("unroll")                                                              \
  for (int reg = 0; reg < 16; ++reg) {                                           \
    int o = ((z * 16 + (Q) * 4 + w) << 5) + (reg & 3) + 8 * (reg >> 2) + 4 * hf; \
    float h = ACC[reg] + bfb[o];                                                 \
    hbf[((long)b * 1024 + o) * 4096 + (nt << 5) + lane31] = f2bf(h);             \
    float vsel = (gf[o] >= 0.f) ? h : -h;                                        \
    _Pragma("unroll")                                                            \
    for (int off = 1; off < 32; off <<= 1)                                       \
      vsel = fmaxf(vsel, __shfl_xor(vsel, off));                                 \
    if (lane31 == 0)                                                             \
      p3[(long)o * 1024 + b * 128 + nt] = vsel;                                  \
  }

__global__ __launch_bounds__(256) void fusion_gemm_store(const ushort* __restrict__ packW,
                                                         const ushort* __restrict__ packB,
                                                         const float* __restrict__ bfb,
                                                         const float* __restrict__ gf,
                                                         int N,
                                                         ushort* __restrict__ hbf,
                                                         float* __restrict__ p3) {
  __shared__ ushort sB[2][12 * 512];
  const int tid = threadIdx.x;
  const int nt = blockIdx.x, z = blockIdx.y, b = blockIdx.z;
  const int w = tid >> 6, l = tid & 63;
  const int lane31 = l & 31, hf = l >> 5;
  const int PB = N >> 5;
  const ushort* srcB = packB + (((long)b * PB + nt) * 96) * 512;

  for (int i = tid * 8; i < 12 * 512; i += 2048)
    __builtin_amdgcn_global_load_lds(
        (const __attribute__((address_space(1))) void*)(srcB + i),
        (__attribute__((address_space(3))) void*)(&sB[0][i]), 16, 0, 0);
  __syncthreads();

  f32x16 acc0 = {}, acc1 = {}, acc2 = {}, acc3 = {};
  const ushort* aw0 = packW + ((long)(z * 16 + 0 + w) * 96) * 512 + l * 8;
  const ushort* aw1 = packW + ((long)(z * 16 + 4 + w) * 96) * 512 + l * 8;
  const ushort* aw2 = packW + ((long)(z * 16 + 8 + w) * 96) * 512 + l * 8;
  const ushort* aw3 = packW + ((long)(z * 16 + 12 + w) * 96) * 512 + l * 8;

  int cur = 0;
  for (int ch = 0; ch < 8; ++ch) {
    if (ch + 1 < 8) {
      const ushort* src = srcB + (ch + 1) * 12 * 512;
      for (int i = tid * 8; i < 12 * 512; i += 2048)
        __builtin_amdgcn_global_load_lds(
            (const __attribute__((address_space(1))) void*)(src + i),
            (__attribute__((address_space(3))) void*)(&sB[cur ^ 1][i]), 16, 0, 0);
    }
    #pragma unroll
    for (int kcl = 0; kcl < 12; ++kcl) {
      const int kc = ch * 12 + kcl;
      bf16x8 bf = *reinterpret_cast<const bf16x8*>(&sB[cur][kcl * 512 + l * 8]);
      bf16x8 a0 = *reinterpret_cast<const bf16x8*>(aw0 + (long)kc * 512);
      acc0 = __builtin_amdgcn_mfma_f32_32x32x16_bf16(a0, bf, acc0, 0, 0, 0);
      bf16x8 a1 = *reinterpret_cast<const bf16x8*>(aw1 + (long)kc * 512);
      acc1 = __builtin_amdgcn_mfma_f32_32x32x16_bf16(a1, bf, acc1, 0, 0, 0);
      bf16x8 a2 = *reinterpret_cast<const bf16x8*>(aw2 + (long)kc * 512);
      acc2 = __builtin_amdgcn_mfma_f32_32x32x16_bf16(a2, bf, acc2, 0, 0, 0);
      bf16x8 a3 = *reinterpret_cast<const bf16x8*>(aw3 + (long)kc * 512);
      acc3 = __builtin_amdgcn_mfma_f32_32x32x16_bf16(a3, bf, acc3, 0, 0, 0);
    }
    __syncthreads();
    cur ^= 1;
  }

  FUS_EPI(acc0, 0)
  FUS_EPI(acc1, 1)
  FUS_EPI(acc2, 2)
  FUS_EPI(acc3, 3)
}

// --------------- BN stats from bf16 h sweep (one wave per (b,o)) ------------
__global__ __launch_bounds__(256) void stats_bf16(const ushort* __restrict__ hbf,
                                                  float* __restrict__ ps1,
                                                  float* __restrict__ ps2) {
  int gw = (blockIdx.x * 256 + threadIdx.x) >> 6;
  int lane = threadIdx.x & 63;
  int b = gw >> 10, o = gw & 1023;
  const ushort* row = hbf + ((long)b * 1024 + o) * 4096;
  float s1 = 0.f, s2 = 0.f;
  for (int j = 0; j < 8; ++j) {
    union { ushort u[8]; short8v v; } hv;
    hv.v = *reinterpret_cast<const short8v*>(row + ((j << 6) + lane) * 8);
    #pragma unroll
    for (int e = 0; e < 8; ++e) {
      float h = __uint_as_float((unsigned)hv.u[e] << 16);
      s1 += h;
      s2 = fmaf(h, h, s2);
    }
  }
  #pragma unroll
  for (int off = 1; off < 64; off <<= 1) {
    s1 += __shfl_xor(s1, off);
    s2 += __shfl_xor(s2, off);
  }
  if (lane == 0) {
    ps1[(long)b * 1024 + o] = s1;
    ps2[(long)b * 1024 + o] = s2;
  }
}

__global__ void finalize_fusion2(const float* __restrict__ ps1, const float* __restrict__ ps2,
                                 const float* __restrict__ g, const float* __restrict__ beta,
                                 float* __restrict__ scale, float* __restrict__ shift) {
  int o = blockIdx.x * 256 + threadIdx.x;
  if (o < 1024) {
    double s1 = 0.0, s2 = 0.0;
    for (int b = 0; b < 8; ++b) {
      s1 += (double)ps1[(long)b * 1024 + o];
      s2 += (double)ps2[(long)b * 1024 + o];
    }
    double invM = 1.0 / 32768.0;
    double mean = s1 * invM;
    double var = s2 * invM - mean * mean;
    double sc = (double)g[o] / sqrt(var + 1e-5);
    scale[o] = (float)sc;
    shift[o] = (float)((double)beta[o] - mean * sc);
  }
}

// --- pool: max from sign-flipped f32 partials, mean from bf16 sweep ---------
__global__ __launch_bounds__(256) void pool_v3(const ushort* __restrict__ hbf,
                                               const float* __restrict__ p3,
                                               const float* __restrict__ scale,
                                               const float* __restrict__ shift,
                                               float* __restrict__ x1x2) {
  int gw = (blockIdx.x * 256 + threadIdx.x) >> 6;
  int lane = threadIdx.x & 63;
  int b = gw >> 10, o = gw & 1023;
  float sc = scale[o], sh = shift[o];

  long pb = (long)o * 1024 + b * 128;
  float red = fmaxf(p3[pb + lane], p3[pb + 64 + lane]);
  #pragma unroll
  for (int off = 1; off < 64; off <<= 1) red = fmaxf(red, __shfl_xor(red, off));
  float hm = (sc >= 0.f) ? red : -red;
  float x1 = LEAKY(fmaf(sc, hm, sh));

  const ushort* row = hbf + ((long)b * 1024 + o) * 4096;
  float sm = 0.f;
  for (int j = 0; j < 8; ++j) {
    union { ushort u[8]; short8v v; } hv;
    hv.v = *reinterpret_cast<const short8v*>(row + ((j << 6) + lane) * 8);
    #pragma unroll
    for (int e = 0; e < 8; ++e) {
      float h = __uint_as_float((unsigned)hv.u[e] << 16);
      float y = fmaf(sc, h, sh);
      sm += LEAKY(y);
    }
  }
  #pragma unroll
  for (int off = 1; off < 64; off <<= 1) sm += __shfl_xor(sm, off);

  if (lane == 0) {
    x1x2[(long)b * 2048 + o] = x1;
    x1x2[(long)b * 2048 + 1024 + o] = sm * (1.f / 4096.f);
  }
}

// ----------------------------------------------------------- classifier -----
__global__ __launch_bounds__(256) void fc_kernel(const float* __restrict__ in, int Cin, int O,
                                                 const float* __restrict__ W,
                                                 const float* __restrict__ bias,
                                                 const float* __restrict__ g,
                                                 const float* __restrict__ beta,
                                                 float* __restrict__ outp, int do_bn) {
  const int tid = threadIdx.x;
  const int o = blockIdx.x * 32 + (tid >> 3);
  const int bb = tid & 7;
  const int oc = (o < O) ? o : (O - 1);
  const float* ir = in + (long)bb * Cin;
  const float* wr = W + (long)oc * Cin;
  float dot = 0.f;
  for (int c = 0; c < Cin; c += 4) {
    float4 a = *reinterpret_cast<const float4*>(&ir[c]);
    float4 w = *reinterpret_cast<const float4*>(&wr[c]);
    dot += a.x * w.x + a.y * w.y + a.z * w.z + a.w * w.w;
  }
  float h = dot + bias[oc];
  if (do_bn) {
    float s = h;
    s += __shfl_xor(s, 1, 8); s += __shfl_xor(s, 2, 8); s += __shfl_xor(s, 4, 8);
    float mean = s * 0.125f;
    float dv = (h - mean) * (h - mean);
    dv += __shfl_xor(dv, 1, 8); dv += __shfl_xor(dv, 2, 8); dv += __shfl_xor(dv, 4, 8);
    float var = dv * 0.125f;
    float y = (h - mean) * (float)(1.0 / sqrt((double)var + 1e-5)) * g[oc] + beta[oc];
    h = LEAKY(y);
  }
  if (o < O) outp[(long)bb * O + o] = h;
}

// ------------------------------------------------------- edge layer driver --
template<int Cin, int O>
static void edge_layer(const float* g, const float* beta,
                       float* featOut, long out_bstride,
                       const ushort* packX6, const ushort* packAwL,
                       float* u, float* v,
                       const int* idx, float* hsel, float* part1, float* part2,
                       float* scale, float* shift, int N, int B,
                       hipStream_t stream) {
  constexpr int KCW = (6 * Cin + 15) / 16;
  constexpr int NOB = O / 32;
  edge_gemm6<KCW, NOB><<<dim3(N / 32, B), 256, 0, stream>>>(packX6, packAwL, N, u, v);
  edge_pass<<<dim3(N / 64, O / 64, B), 256, 0, stream>>>(u, v, idx, g, O, N, hsel, part1, part2);
  finalize_scale<<<(O * 64 + 255) / 256, 256, 0, stream>>>(part1, part2, g, beta,
                                                           1.0 / ((double)B * N * 9), O,
                                                           scale, shift);
  edge_out<<<dim3(N / 64, B), 256, 0, stream>>>(hsel, scale, shift, O, N, featOut, out_bstride);
}

// ---------------------------------------------------------------- driver ----
extern "C" void kernel_launch(void* const* d_in, const int* in_sizes, int n_in,
                              void* d_out, int out_size, void* d_ws, size_t ws_size,
                              hipStream_t stream) {
  const int B = 8, N = 4096;
  const float* x   = (const float*)d_in[0];
  const float* w1 = (const float*)d_in[2];  const float* g1 = (const float*)d_in[3];  const float* b1 = (const float*)d_in[4];
  const float* w2 = (const float*)d_in[5];  const float* g2 = (const float*)d_in[6];  const float* b2 = (const float*)d_in[7];
  const float* w3 = (const float*)d_in[8];  const float* g3 = (const float*)d_in[9];  const float* b3 = (const float*)d_in[10];
  const float* w4 = (const float*)d_in[11]; const float* g4 = (const float*)d_in[12]; const float* b4 = (const float*)d_in[13];
  const float* wf = (const float*)d_in[14]; const float* bfv = (const float*)d_in[15];
  const float* gf = (const float*)d_in[16]; const float* betaf = (const float*)d_in[17];
  const float* wc1 = (const float*)d_in[18]; const float* bc1 = (const float*)d_in[19];
  const float* gc1 = (const float*)d_in[20]; const float* betac1 = (const float*)d_in[21];
  const float* wc2 = (const float*)d_in[22]; const float* bc2 = (const float*)d_in[23];
  const float* gc2 = (const float*)d_in[24]; const float* betac2 = (const float*)d_in[25];
  const float* wc3 = (const float*)d_in[26]; const float* bc3 = (const float*)d_in[27];

  char* p = (char*)d_ws;
  auto alloc = [&](size_t bytes) -> char* {
    char* r = p;
    p += (bytes + 255) & ~(size_t)255;
    return r;
  };
  float* feat  = (float*)alloc((size_t)B * 512 * N * 4);
  int*   idx   = (int*)  alloc((size_t)B * N * 9 * 4);
  int*   cand  = (int*)  alloc((size_t)B * N * 64 * 4);
  float* xxg   = (float*)alloc((size_t)B * N * 4);
  float* u     = (float*)alloc((size_t)B * N * 256 * 4);
  float* v     = (float*)alloc((size_t)B * N * 256 * 4);
  float* hmax  = (float*)alloc((size_t)B * N * 256 * 4);
  float* hmin  = (float*)alloc((size_t)B * N * 256 * 4);
  ushort* packR = (ushort*)u;
  ushort* packC = (ushort*)v;
  ushort* packX6 = (ushort*)hmax;
  float*  xpm   = (float*)((char*)hmin + 16777216);
  float*  hsel  = hmax;
  float*  part1 = hmin;
  float*  part2 = hmin + 131072;
  ushort* packB = (ushort*)u;
  ushort* hbf   = (ushort*)feat;
  float*  ps1   = hmin;
  float*  ps2   = hmin + 1048576;
  float*  ps3   = hmin + 2 * 1048576;
  ushort* packAw = (ushort*)alloc((size_t)544768 * 2);
  ushort* packW = (ushort*)alloc((size_t)32 * 96 * 512 * 2);
  float* scale = (float*)alloc(1024 * 4);
  float* shift = (float*)alloc(1024 * 4);
  float* x1x2  = (float*)alloc((size_t)B * 2048 * 4);
  float* h1    = (float*)alloc((size_t)B * 512 * 4);
  float* h2    = (float*)alloc((size_t)B * 256 * 4);

  const ushort* pawL1 = packAw;
  const ushort* pawL2 = packAw + 4096;
  const ushort* pawL3 = packAw + 53248;
  const ushort* pawL4 = packAw + 151552;

  dim3 gpack(N / 32, B);
  dim3 gknn4(N / 128, B, 4);
  dim3 grr40(N / 8, B);

  pack3_wf<<<32, 256, 0, stream>>>(wf, packW);
  pack6_w_all<<<32, 256, 0, stream>>>(w1, w2, w3, w4, packAw);

  // layer 1: C=3 (KCc=1, KCX=2)
  pack_layer<3, 1, 2><<<gpack, 256, 0, stream>>>(x, (long)3 * N, N, xxg,
                                                 packR, packC, xpm, packX6);
  knn_v5<1, 4, 4><<<gknn4, 256, 0, stream>>>(packR, packC, xxg, N, cand);
  rerank_kernel<3, 40><<<grr40, 320, 0, stream>>>(xpm, N, xxg, cand, idx);
  edge_layer<3, 64>(g1, b1, feat, (long)512 * N, packX6, pawL1, u, v, idx,
                    hsel, part1, part2, scale, shift, N, B, stream);

  // layer 2: C=64 (KCc=13, KCX=24)
  pack_layer<64, 13, 24><<<gpack, 256, 0, stream>>>(feat, (long)512 * N, N, xxg,
                                                    packR, packC, xpm, packX6);
  knn_v5<13, 3, 4><<<gknn4, 256, 0, stream>>>(packR, packC, xxg, N, cand);
  rerank_kernel<64, 40><<<grr40, 320, 0, stream>>>(xpm, N, xxg, cand, idx);
  edge_layer<64, 64>(g2, b2, feat + (long)64 * N, (long)512 * N, packX6, pawL2,
                     u, v, idx, hsel, part1, part2, scale, shift, N, B, stream);

  // layer 3: C=64
  pack_layer<64, 13, 24><<<gpack, 256, 0, stream>>>(feat + (long)64 * N, (long)512 * N, N, xxg,
                                                    packR, packC, xpm, packX6);
  knn_v5<13, 3, 4><<<gknn4, 256, 0, stream>>>(packR, packC, xxg, N, cand);
  rerank_kernel<64, 40><<<grr40, 320, 0, stream>>>(xpm, N, xxg, cand, idx);
  edge_layer<64, 128>(g3, b3, feat + (long)128 * N, (long)512 * N, packX6, pawL3,
                      u, v, idx, hsel, part1, part2, scale, shift, N, B, stream);

  // layer 4: C=128 (KCc=25, KCX=48; z=4 — r18 isolated re-test of r11 config)
  pack_layer<128, 25, 48><<<gpack, 256, 0, stream>>>(feat + (long)128 * N, (long)512 * N, N, xxg,
                                                     packR, packC, xpm, packX6);
  knn_v5<25, 3, 4><<<gknn4, 256, 0, stream>>>(packR, packC, xxg, N, cand);
  rerank_kernel<128, 40><<<grr40, 320, 0, stream>>>(xpm, N, xxg, cand, idx);
  edge_layer<128, 256>(g4, b4, feat + (long)256 * N, (long)512 * N, packX6, pawL4,
                       u, v, idx, hsel, part1, part2, scale, shift, N, B, stream);

  // fusion conv 512->1024 (z=2, 4 accs/wave)
  pack3_feat<<<dim3(N / 32, B), 256, 0, stream>>>(feat, N, packB);
  dim3 gfu(N / 32, 2, B);
  fusion_gemm_store<<<gfu, 256, 0, stream>>>(packW, packB, bfv, gf, N, hbf, ps3);
  stats_bf16<<<2048, 256, 0, stream>>>(hbf, ps1, ps2);
  finalize_fusion2<<<4, 256, 0, stream>>>(ps1, ps2, gf, betaf, scale, shift);
  pool_v3<<<2048, 256, 0, stream>>>(hbf, ps3, scale, shift, x1x2);

  fc_kernel<<<16, 256, 0, stream>>>(x1x2, 2048, 512, wc1, bc1, gc1, betac1, h1, 1);
  fc_kernel<<<8, 256, 0, stream>>>(h1, 512, 256, wc2, bc2, gc2, betac2, h2, 1);
  fc_kernel<<<2, 256, 0, stream>>>(h2, 256, 40, wc3, bc3, nullptr, nullptr, (float*)d_out, 0);
}

// Round 19
// 1373.775 us; speedup vs baseline: 1.0303x; 1.0303x over previous
//
#include <hip/hip_runtime.h>
#include <math.h>
#include <float.h>

// DGCNN forward, MI355X.  (r19 = exact revert to r17, the measured best.)
// kNN: 3-term split-bf16 MFMA approx distances (xx folded into GEMM) ->
//      packed-key top-10 per partition -> exact f32 re-rank (r2 rounding).
// Edge u/v GEMMs: 6-term split-bf16 MFMA (error ~1e-9 rel = f32 class).
// pack_layer: ONE pass emits xxg + kNN packs + xpm + 6-term GEMM pack.
// pack6_w_all: all 4 layers' weights packed in one dispatch.
// Edge stats: non-atomic partials; finalize = 1 wave/channel double reduce.
// Fusion: z=2, 4 accs/wave; bf16 h + sign-selected f32 extrema; stats sweep.
// L4 kNN: z=2, rerank pool 20 (Z=4 A/B-tested in r18: -40us regression).

#define LEAKY(y) ((y) >= 0.f ? (y) : 0.2f * (y))

using f32x16 = __attribute__((ext_vector_type(16))) float;
using bf16x8 = __attribute__((ext_vector_type(8))) __bf16;
using short8v = __attribute__((ext_vector_type(8))) short;

__device__ inline ushort f2bf(float x) {
  unsigned u = __float_as_uint(x);
  unsigned r = (u + 0x7fff + ((u >> 16) & 1)) >> 16;
  return (ushort)r;
}

// ---- merged per-layer pack: xx + kNN 3-term packs + xpm + 6-term GEMM pack -
template<int C, int KCc, int KCX>
__global__ __launch_bounds__(256) void pack_layer(const float* __restrict__ xin, long bstride,
                                                  int N, float* __restrict__ xxg,
                                                  ushort* __restrict__ packR,
                                                  ushort* __restrict__ packC,
                                                  float* __restrict__ xpm,
                                                  ushort* __restrict__ packX6) {
  __shared__ float xt[C][32];
  __shared__ float sxx[32];
  const int tid = threadIdx.x;
  const int pb = blockIdx.x, b = blockIdx.y;
  for (int i = tid; i < C * 32; i += 256) {
    int c = i >> 5, j = i & 31;
    xt[c][j] = xin[(long)b * bstride + (long)c * N + pb * 32 + j];
  }
  __syncthreads();
  if (tid < 32) {
    float s = 0.f;
    for (int c = 0; c < C; ++c) { float t = xt[c][tid]; s += t * t; }
    sxx[tid] = s;
    xxg[(long)b * N + pb * 32 + tid] = s;
  }
  __syncthreads();
  for (int i = tid; i < 32 * C; i += 256) {
    int pt = i / C, c = i % C;
    xpm[((long)b * N + pb * 32 + pt) * C + c] = xt[c][pt];
  }
  const int PB = N >> 5;
  for (int it = tid; it < KCc * 64; it += 256) {
    int kc = it >> 6, l = it & 63;
    int pt = l & 31;
    union { ushort u[8]; short8v v; } R, Cc;
    #pragma unroll
    for (int e = 0; e < 8; ++e) {
      int kp = kc * 16 + ((l >> 5) << 3) + e;
      ushort rv = 0, cv = 0;
      if (kp < 3 * C) {
        int s = kp / C, c = kp % C;
        float xv = xt[c][pt];
        ushort hi = f2bf(xv);
        float hif = __uint_as_float((unsigned)hi << 16);
        ushort mid = f2bf(xv - hif);
        rv = (s == 2) ? mid : hi;
        cv = (s == 1) ? mid : hi;
      } else if (kp == 3 * C) {
        float xxv = sxx[pt];
        cv = f2bf(xxv);
        rv = 0xBF00;                       // bf16(-0.5), exact
      } else if (kp == 3 * C + 1) {
        float xxv = sxx[pt];
        ushort hi = f2bf(xxv);
        float hif = __uint_as_float((unsigned)hi << 16);
        cv = f2bf(xxv - hif);
        rv = 0xBF00;
      }
      R.u[e] = rv; Cc.u[e] = cv;
    }
    long off = (((long)b * PB + pb) * KCc + kc) * 512 + l * 8;
    *reinterpret_cast<short8v*>(&packR[off]) = R.v;
    *reinterpret_cast<short8v*>(&packC[off]) = Cc.v;
  }
  for (int it = tid; it < KCX * 64; it += 256) {
    int kc = it >> 6, l = it & 63;
    int pt = l & 31;
    union { ushort u[8]; short8v v; } P;
    #pragma unroll
    for (int e = 0; e < 8; ++e) {
      int kp = kc * 16 + ((l >> 5) << 3) + e;
      ushort val = 0;
      if (kp < 6 * C) {
        int s = kp / C, c = kp % C;
        float xv = xt[c][pt];
        ushort hi = f2bf(xv);
        float hif = __uint_as_float((unsigned)hi << 16);
        float r1 = xv - hif;
        ushort mid = f2bf(r1);
        float midf = __uint_as_float((unsigned)mid << 16);
        ushort lo = f2bf(r1 - midf);
        val = (s == 1 || s == 3) ? mid : ((s == 4) ? lo : hi);
      }
      P.u[e] = val;
    }
    long off = (((long)b * PB + pb) * KCX + kc) * 512 + l * 8;
    *reinterpret_cast<short8v*>(&packX6[off]) = P.v;
  }
}

// ----------------------------------------------------- kNN phase 1 (MFMA) ---
#define KNN_SCAN(SELF)                                            \
  _Pragma("unroll")                                               \
  for (int reg = 0; reg < 16; ++reg) {                            \
    int m_loc = (reg & 3) + 8 * (reg >> 2) + 4 * hf;              \
    float d = fmaf(-2.0f, acc[reg], xr);                          \
    d = fmaxf(d, 0.f);                                            \
    unsigned key = (__float_as_uint(d) & KEYMASK) |               \
                   (unsigned)((t << 5) | m_loc);                  \
    if (SELF && ((mb << 5) | m_loc) == n_glob) key = 0xFFFFFFFFu; \
    if (key < tk[9]) {                                            \
      unsigned kc = key;                                          \
      _Pragma("unroll")                                           \
      for (int s_ = 0; s_ < 10; ++s_) {                           \
        unsigned mn_ = min(kc, tk[s_]);                           \
        kc = max(kc, tk[s_]);                                     \
        tk[s_] = mn_;                                             \
      }                                                           \
    }                                                             \
  }

template<int KCc, int MINW, int Z>
__global__ __launch_bounds__(256, MINW) void knn_v5(const ushort* __restrict__ packR,
                                                    const ushort* __restrict__ packC,
                                                    const float* __restrict__ xxg,
                                                    int N, int* __restrict__ cand) {
  constexpr int SA_ELEMS = KCc * 512;
  constexpr int SA_BYTES = SA_ELEMS * 2;
  constexpr int POOL = (2 * SA_BYTES > 10240) ? 2 * SA_BYTES : 10240;
  __shared__ __align__(16) char smem[POOL];
  ushort* const sA0 = (ushort*)smem;
  ushort* const sA1 = (ushort*)(smem + SA_BYTES);

  const int tid = threadIdx.x;
  const int b = blockIdx.y, rowblk = blockIdx.x, z = blockIdx.z;
  const int w = tid >> 6, l = tid & 63;
  const int lane31 = l & 31, hf = l >> 5;
  const int PB = N >> 5;
  const int HALF = PB / Z;
  const unsigned IDXMASK = (unsigned)(HALF * 32 - 1);
  const unsigned KEYMASK = ~IDXMASK;
  const int myblk = rowblk * 4 + w;

  const ushort* rp = packR + (((long)b * PB + myblk) * (long)KCc) * 512 + l * 8;
  bf16x8 bfr[KCc];
  #pragma unroll
  for (int kc = 0; kc < KCc; ++kc)
    bfr[kc] = *reinterpret_cast<const bf16x8*>(rp + kc * 512);

  const ushort* srcb = packC + ((long)b * PB) * (long)SA_ELEMS;
  const int mb0 = z * HALF;

  {
    const ushort* src = srcb + (long)mb0 * SA_ELEMS;
    for (int i = tid * 8; i < SA_ELEMS; i += 2048)
      __builtin_amdgcn_global_load_lds(
          (const __attribute__((address_space(1))) void*)(src + i),
          (__attribute__((address_space(3))) void*)(sA0 + i), 16, 0, 0);
  }

  const int n_glob = rowblk * 128 + w * 32 + lane31;
  const float xr = xxg[(long)b * N + n_glob];

  unsigned tk[10];
  #pragma unroll
  for (int s = 0; s < 10; ++s) tk[s] = 0xFFFFFFFFu;

  __syncthreads();

  for (int t = 0; t < HALF; ++t) {
    const int mb = mb0 + t;
    const ushort* curA = (t & 1) ? sA1 : sA0;
    ushort* nxtA = (t & 1) ? sA0 : sA1;
    if (t + 1 < HALF) {
      const ushort* src = srcb + (long)(mb + 1) * SA_ELEMS;
      for (int i = tid * 8; i < SA_ELEMS; i += 2048)
        __builtin_amdgcn_global_load_lds(
            (const __attribute__((address_space(1))) void*)(src + i),
            (__attribute__((address_space(3))) void*)(nxtA + i), 16, 0, 0);
    }
    f32x16 acc = {};
    #pragma unroll
    for (int kc = 0; kc < KCc; ++kc) {
      bf16x8 af = *reinterpret_cast<const bf16x8*>(curA + kc * 512 + l * 8);
      acc = __builtin_amdgcn_mfma_f32_32x32x16_bf16(af, bfr[kc], acc, 0, 0, 0);
    }
    if (mb == myblk) {
      KNN_SCAN(true)
    } else {
      KNN_SCAN(false)
    }
    __syncthreads();
  }

  unsigned* mK = (unsigned*)smem;
  const int row = w * 32 + lane31;
  #pragma unroll
  for (int s = 0; s < 10; ++s)
    mK[row * 20 + hf * 10 + s] = tk[s];
  __syncthreads();
  if (tid < 128) {
    int p0 = 0, p1 = 0;
    const long ob = ((long)b * N + rowblk * 128 + tid) * (Z * 10) + z * 10;
    const int base_m = z * HALF * 32;
    for (int s = 0; s < 10; ++s) {
      unsigned k0 = mK[tid * 20 + p0];
      unsigned k1 = mK[tid * 20 + 10 + p1];
      bool t0 = k0 < k1;
      unsigned kk = t0 ? k0 : k1;
      cand[ob + s] = base_m + (int)(kk & IDXMASK);
      if (t0) ++p0; else ++p1;
    }
  }
}

// ---------------- exact f32 re-rank of P candidates (point-major input) -----
template<int C, int P>
__global__ __launch_bounds__(320) void rerank_kernel(const float* __restrict__ xpm,
                                                     int N, const float* __restrict__ xxg,
                                                     const int* __restrict__ cand,
                                                     int* __restrict__ idx_out) {
  constexpr int ROWS = 320 / P;
  __shared__ float sq[ROWS][C];
  __shared__ float sd[ROWS][P + 1];
  __shared__ int   si[ROWS][P + 1];
  const int tid = threadIdx.x;
  const int b = blockIdx.y, n0 = blockIdx.x * ROWS;
  const float* xb = xpm + (long)b * N * C;
  for (int i = tid; i < ROWS * C; i += 320) {
    int r = i / C, c = i % C;
    sq[r][c] = xb[(long)(n0 + r) * C + c];
  }
  __syncthreads();
  const int r = tid / P, j = tid % P;
  const int n = n0 + r;
  const int m = cand[((long)b * N + n) * P + j];
  const float* cv = xb + (long)m * C;
  float dot = 0.f;
  if constexpr ((C & 3) == 0) {
    for (int c = 0; c < C; c += 4) {
      float4 v4 = *reinterpret_cast<const float4*>(cv + c);
      dot = fmaf(sq[r][c + 0], v4.x, dot);
      dot = fmaf(sq[r][c + 1], v4.y, dot);
      dot = fmaf(sq[r][c + 2], v4.z, dot);
      dot = fmaf(sq[r][c + 3], v4.w, dot);
    }
  } else {
    for (int c = 0; c < C; ++c) dot = fmaf(sq[r][c], cv[c], dot);
  }
  float d = (xxg[(long)b * N + n] - 2.0f * dot) + xxg[(long)b * N + m];
  if (m == n) d = 3.0e38f;
  sd[r][j] = d; si[r][j] = m;
  __syncthreads();
  int rank = 0;
  #pragma unroll
  for (int t = 0; t < P; ++t) {
    float dd = sd[r][t]; int ii = si[r][t];
    if (dd < d || (dd == d && ii < m)) rank++;
  }
  if (rank < 9) idx_out[((long)b * N + n) * 9 + rank] = m;
}

// ---------------- ALL edge weight packs in one dispatch (6-term split) ------
__global__ __launch_bounds__(256) void pack6_w_all(const float* __restrict__ w1,
                                                   const float* __restrict__ w2,
                                                   const float* __restrict__ w3,
                                                   const float* __restrict__ w4,
                                                   ushort* __restrict__ packAw) {
  __shared__ float wt[32][129];
  const int mo = blockIdx.x;
  const int tid = threadIdx.x;
  int C, NOB, moL; long base; const float* W;
  if (mo < 4)       { C = 3;   NOB = 2; moL = mo;      base = 0;               W = w1; }
  else if (mo < 8)  { C = 64;  NOB = 2; moL = mo - 4;  base = 4096;            W = w2; }
  else if (mo < 16) { C = 64;  NOB = 4; moL = mo - 8;  base = 53248;           W = w3; }
  else              { C = 128; NOB = 8; moL = mo - 16; base = 151552;          W = w4; }
  const int KCW = (6 * C + 15) / 16;
  const int mat = moL / NOB, ob = moL % NOB;
  for (int i = tid; i < 32 * C; i += 256) {
    int o = i / C, c = i % C;
    float w1v = W[(long)(ob * 32 + o) * 2 * C + c];
    float w2v = W[(long)(ob * 32 + o) * 2 * C + C + c];
    wt[o][c] = mat ? w2v : (w1v - w2v);
  }
  __syncthreads();
  ushort* dst = packAw + base + (long)moL * KCW * 512;
  for (int it = tid; it < KCW * 64; it += 256) {
    int kc = it >> 6, l = it & 63;
    union { ushort u[8]; short8v v; } P;
    #pragma unroll
    for (int e = 0; e < 8; ++e) {
      int kp = kc * 16 + ((l >> 5) << 3) + e;
      ushort val = 0;
      if (kp < 6 * C) {
        int s = kp / C, c = kp % C;
        float xv = wt[l & 31][c];
        ushort hi = f2bf(xv);
        float hif = __uint_as_float((unsigned)hi << 16);
        float r1 = xv - hif;
        ushort mid = f2bf(r1);
        float midf = __uint_as_float((unsigned)mid << 16);
        ushort lo = f2bf(r1 - midf);
        val = (s == 2 || s == 3) ? mid : ((s == 5) ? lo : hi);
      }
      P.u[e] = val;
    }
    *reinterpret_cast<short8v*>(&dst[((long)kc) * 512 + l * 8]) = P.v;
  }
}

// ------------- edge u,v GEMM on MFMA: D[o][n] = sum W'[o][k'] X[n][k'] ------
template<int KCW, int NOB>
__global__ __launch_bounds__(256) void edge_gemm6(const ushort* __restrict__ packX,
                                                  const ushort* __restrict__ packAw,
                                                  int N,
                                                  float* __restrict__ u,
                                                  float* __restrict__ v) {
  constexpr int NT = 2 * NOB;
  constexpr int TPW = NT / 4;
  constexpr int O = NOB * 32;
  const int nb = blockIdx.x, b = blockIdx.y;
  const int w = threadIdx.x >> 6, l = threadIdx.x & 63;
  const int lane31 = l & 31, hf = l >> 5;
  const ushort* xp = packX + ((long)(b * (N >> 5) + nb) * KCW) * 512 + l * 8;

  f32x16 acc[TPW] = {};
  const ushort* aptr[TPW];
  #pragma unroll
  for (int ti = 0; ti < TPW; ++ti) {
    int t = w + ti * 4;
    int mat = t & 1, ob = t >> 1;
    aptr[ti] = packAw + ((long)(mat * NOB + ob) * KCW) * 512 + l * 8;
  }

  for (int kc = 0; kc < KCW; ++kc) {
    bf16x8 bf = *reinterpret_cast<const bf16x8*>(xp + (long)kc * 512);
    #pragma unroll
    for (int ti = 0; ti < TPW; ++ti) {
      bf16x8 af = *reinterpret_cast<const bf16x8*>(aptr[ti] + (long)kc * 512);
      acc[ti] = __builtin_amdgcn_mfma_f32_32x32x16_bf16(af, bf, acc[ti], 0, 0, 0);
    }
  }

  #pragma unroll
  for (int ti = 0; ti < TPW; ++ti) {
    int t = w + ti * 4;
    int mat = t & 1, ob = t >> 1;
    float* dst = mat ? v : u;
    long rowbase = ((long)b * N + nb * 32 + lane31) * O + ob * 32;
    #pragma unroll
    for (int q = 0; q < 4; ++q) {
      float4 st = make_float4(acc[ti][4 * q + 0], acc[ti][4 * q + 1],
                              acc[ti][4 * q + 2], acc[ti][4 * q + 3]);
      *reinterpret_cast<float4*>(&dst[rowbase + 4 * hf + 8 * q]) = st;
    }
  }
}

// -------- gather pass: stats partials + sign-selected extremum hsel ---------
__global__ __launch_bounds__(256) void edge_pass(const float* __restrict__ u,
                                                 const float* __restrict__ v,
                                                 const int* __restrict__ idx,
                                                 const float* __restrict__ g,
                                                 int O, int N,
                                                 float* __restrict__ hsel,
                                                 float* __restrict__ part1,
                                                 float* __restrict__ part2) {
  const int tid = threadIdx.x;
  const int n0 = blockIdx.x * 64, o0 = blockIdx.y * 64, b = blockIdx.z;
  __shared__ int sidx[64][9];
  __shared__ float4 redA[4][16];
  __shared__ float4 redB[4][16];
  for (int i = tid; i < 576; i += 256)
    ((int*)sidx)[i] = idx[((long)b * N + n0) * 9 + i];
  __syncthreads();
  const int nl = tid >> 4, oq = tid & 15;
  const long base = (long)b * N;
  const int ocol = o0 + 4 * oq;
  const float4 gv = *reinterpret_cast<const float4*>(&g[ocol]);
  float4 s1 = make_float4(0.f, 0.f, 0.f, 0.f);
  float4 s2 = make_float4(0.f, 0.f, 0.f, 0.f);
  for (int gg = 0; gg < 4; ++gg) {
    const int n = gg * 16 + nl;
    const float4 u4 = *reinterpret_cast<const float4*>(&u[(base + n0 + n) * O + ocol]);
    float4 mx = make_float4(-3.0e38f, -3.0e38f, -3.0e38f, -3.0e38f);
    float4 mn = make_float4(3.0e38f, 3.0e38f, 3.0e38f, 3.0e38f);
    #pragma unroll
    for (int k = 0; k < 9; ++k) {
      int m = sidx[n][k];
      const float4 v4 = *reinterpret_cast<const float4*>(&v[(base + m) * O + ocol]);
      float hx = u4.x + v4.x, hy = u4.y + v4.y, hz = u4.z + v4.z, hw = u4.w + v4.w;
      s1.x += hx; s1.y += hy; s1.z += hz; s1.w += hw;
      s2.x = fmaf(hx, hx, s2.x); s2.y = fmaf(hy, hy, s2.y);
      s2.z = fmaf(hz, hz, s2.z); s2.w = fmaf(hw, hw, s2.w);
      mx.x = fmaxf(mx.x, hx); mx.y = fmaxf(mx.y, hy); mx.z = fmaxf(mx.z, hz); mx.w = fmaxf(mx.w, hw);
      mn.x = fminf(mn.x, hx); mn.y = fminf(mn.y, hy); mn.z = fminf(mn.z, hz); mn.w = fminf(mn.w, hw);
    }
    float4 sel;
    sel.x = (gv.x >= 0.f) ? mx.x : mn.x;
    sel.y = (gv.y >= 0.f) ? mx.y : mn.y;
    sel.z = (gv.z >= 0.f) ? mx.z : mn.z;
    sel.w = (gv.w >= 0.f) ? mx.w : mn.w;
    *reinterpret_cast<float4*>(&hsel[(base + n0 + n) * O + ocol]) = sel;
  }
  s1.x += __shfl_xor(s1.x, 16); s1.y += __shfl_xor(s1.y, 16);
  s1.z += __shfl_xor(s1.z, 16); s1.w += __shfl_xor(s1.w, 16);
  s2.x += __shfl_xor(s2.x, 16); s2.y += __shfl_xor(s2.y, 16);
  s2.z += __shfl_xor(s2.z, 16); s2.w += __shfl_xor(s2.w, 16);
  s1.x += __shfl_xor(s1.x, 32); s1.y += __shfl_xor(s1.y, 32);
  s1.z += __shfl_xor(s1.z, 32); s1.w += __shfl_xor(s1.w, 32);
  s2.x += __shfl_xor(s2.x, 32); s2.y += __shfl_xor(s2.y, 32);
  s2.z += __shfl_xor(s2.z, 32); s2.w += __shfl_xor(s2.w, 32);
  if ((tid & 48) == 0) { redA[tid >> 6][oq] = s1; redB[tid >> 6][oq] = s2; }
  __syncthreads();
  if (tid < 16) {
    float4 a = redA[0][tid], bb = redB[0][tid];
    #pragma unroll
    for (int ww = 1; ww < 4; ++ww) {
      float4 t1 = redA[ww][tid], t2 = redB[ww][tid];
      a.x += t1.x; a.y += t1.y; a.z += t1.z; a.w += t1.w;
      bb.x += t2.x; bb.y += t2.y; bb.z += t2.z; bb.w += t2.w;
    }
    int o = o0 + 4 * tid;
    int part = b * gridDim.x + blockIdx.x;
    part1[(long)(o + 0) * 512 + part] = a.x;  part2[(long)(o + 0) * 512 + part] = bb.x;
    part1[(long)(o + 1) * 512 + part] = a.y;  part2[(long)(o + 1) * 512 + part] = bb.y;
    part1[(long)(o + 2) * 512 + part] = a.z;  part2[(long)(o + 2) * 512 + part] = bb.z;
    part1[(long)(o + 3) * 512 + part] = a.w;  part2[(long)(o + 3) * 512 + part] = bb.w;
  }
}

// -------- finalize: one wave per channel, double shuffle reduce -------------
__global__ __launch_bounds__(256) void finalize_scale(const float* __restrict__ part1,
                                                      const float* __restrict__ part2,
                                                      const float* __restrict__ g,
                                                      const float* __restrict__ beta,
                                                      double invM, int O,
                                                      float* __restrict__ scale,
                                                      float* __restrict__ shift) {
  int o = (blockIdx.x * 256 + threadIdx.x) >> 6;   // one wave per channel
  int lane = threadIdx.x & 63;
  if (o >= O) return;
  double s1 = 0.0, s2 = 0.0;
  #pragma unroll
  for (int j = 0; j < 8; ++j) {
    int k = j * 64 + lane;
    s1 += (double)part1[(long)o * 512 + k];
    s2 += (double)part2[(long)o * 512 + k];
  }
  #pragma unroll
  for (int off = 1; off < 64; off <<= 1) {
    s1 += __shfl_xor(s1, off);
    s2 += __shfl_xor(s2, off);
  }
  if (lane == 0) {
    double mean = s1 * invM;
    double var = s2 * invM - mean * mean;
    double sc = (double)g[o] / sqrt(var + 1e-5);
    scale[o] = (float)sc;
    shift[o] = (float)((double)beta[o] - mean * sc);
  }
}

// ------------------- elementwise finalize + transpose to (B,O,N) ------------
__global__ __launch_bounds__(256) void edge_out(const float* __restrict__ hsel,
                                                const float* __restrict__ scale,
                                                const float* __restrict__ shift,
                                                int O, int N,
                                                float* __restrict__ outp, long out_bstride) {
  const int tid = threadIdx.x;
  const int b = blockIdx.y, n0 = blockIdx.x * 64;
  __shared__ float yt[64][65];
  const int ol = tid & 63, nl = tid >> 6;
  const long base = (long)b * N;
  for (int oc = 0; oc < O; oc += 64) {
    float sc = scale[oc + ol], sh = shift[oc + ol];
    __syncthreads();
    for (int ng = 0; ng < 16; ++ng) {
      int n = ng * 4 + nl;
      float hv = hsel[(base + n0 + n) * O + oc + ol];
      float y = sc * hv + sh;
      yt[ol][n] = LEAKY(y);
    }
    __syncthreads();
    for (int rr = 0; rr < 16; ++rr) {
      int r = rr * 4 + nl;
      outp[(long)b * out_bstride + (long)(oc + r) * N + n0 + ol] = yt[r][ol];
    }
  }
}

// ----------------- fusion packs: weights (A-pattern), feat (B-pattern) ------
__global__ __launch_bounds__(256) void pack3_wf(const float* __restrict__ wf,
                                                ushort* __restrict__ packW) {
  __shared__ float wt[32][129];
  const int po = blockIdx.x;
  const int tid = threadIdx.x;
  for (int c0 = 0; c0 < 512; c0 += 128) {
    __syncthreads();
    for (int i = tid; i < 32 * 128; i += 256) {
      int o = i >> 7, c = i & 127;
      wt[o][c] = wf[(long)(po * 32 + o) * 512 + c0 + c];
    }
    __syncthreads();
    #pragma unroll
    for (int s = 0; s < 3; ++s) {
      int kc0 = (s * 512 + c0) >> 4;
      for (int it = tid; it < 8 * 64; it += 256) {
        int kcl = it >> 6, l = it & 63;
        union { ushort u[8]; short8v v; } P;
        #pragma unroll
        for (int e = 0; e < 8; ++e) {
          int kp = (kc0 + kcl) * 16 + ((l >> 5) << 3) + e;
          int c = kp - s * 512 - c0;
          float xv = wt[l & 31][c];
          ushort hi = f2bf(xv);
          if (s == 1) {
            float hif = __uint_as_float((unsigned)hi << 16);
            P.u[e] = f2bf(xv - hif);
          } else P.u[e] = hi;
        }
        *reinterpret_cast<short8v*>(&packW[((long)po * 96 + kc0 + kcl) * 512 + l * 8]) = P.v;
      }
    }
  }
}

__global__ __launch_bounds__(256) void pack3_feat(const float* __restrict__ feat, int N,
                                                  ushort* __restrict__ packB) {
  __shared__ float xt[64][33];
  const int pb = blockIdx.x, b = blockIdx.y;
  const int tid = threadIdx.x;
  const int PB = N >> 5;
  for (int c0 = 0; c0 < 512; c0 += 64) {
    __syncthreads();
    for (int i = tid; i < 64 * 32; i += 256) {
      int c = i >> 5, j = i & 31;
      xt[c][j] = feat[((long)b * 512 + c0 + c) * N + pb * 32 + j];
    }
    __syncthreads();
    #pragma unroll
    for (int s = 0; s < 3; ++s) {
      int kc0 = (s * 512 + c0) >> 4;
      for (int it = tid; it < 4 * 64; it += 256) {
        int kcl = it >> 6, l = it & 63;
        union { ushort u[8]; short8v v; } P;
        #pragma unroll
        for (int e = 0; e < 8; ++e) {
          int kp = (kc0 + kcl) * 16 + ((l >> 5) << 3) + e;
          int c = kp - s * 512 - c0;
          float xv = xt[c][l & 31];
          ushort hi = f2bf(xv);
          if (s == 2) {
            float hif = __uint_as_float((unsigned)hi << 16);
            P.u[e] = f2bf(xv - hif);
          } else P.u[e] = hi;
        }
        *reinterpret_cast<short8v*>(
            &packB[(((long)b * PB + pb) * 96 + kc0 + kcl) * 512 + l * 8]) = P.v;
      }
    }
  }
}

// --- fusion MFMA: z=2, 4 accs/wave; bf16 h + sign-selected extremum ---------
#define FUS_EPI(ACC, Q)                                                          \
  _Pragma("unroll")                                                              \
  for (int reg = 0; reg < 16; ++reg) {                                           \
    int o = ((z * 16 + (Q) * 4 + w) << 5) + (reg & 3) + 8 * (reg >> 2) + 4 * hf; \
    float h = ACC[reg] + bfb[o];                                                 \
    hbf[((long)b * 1024 + o) * 4096 + (nt << 5) + lane31] = f2bf(h);             \
    float vsel = (gf[o] >= 0.f) ? h : -h;                                        \
    _Pragma("unroll")                                                            \
    for (int off = 1; off < 32; off <<= 1)                                       \
      vsel = fmaxf(vsel, __shfl_xor(vsel, off));                                 \
    if (lane31 == 0)                                                             \
      p3[(long)o * 1024 + b * 128 + nt] = vsel;                                  \
  }

__global__ __launch_bounds__(256) void fusion_gemm_store(const ushort* __restrict__ packW,
                                                         const ushort* __restrict__ packB,
                                                         const float* __restrict__ bfb,
                                                         const float* __restrict__ gf,
                                                         int N,
                                                         ushort* __restrict__ hbf,
                                                         float* __restrict__ p3) {
  __shared__ ushort sB[2][12 * 512];
  const int tid = threadIdx.x;
  const int nt = blockIdx.x, z = blockIdx.y, b = blockIdx.z;
  const int w = tid >> 6, l = tid & 63;
  const int lane31 = l & 31, hf = l >> 5;
  const int PB = N >> 5;
  const ushort* srcB = packB + (((long)b * PB + nt) * 96) * 512;

  for (int i = tid * 8; i < 12 * 512; i += 2048)
    __builtin_amdgcn_global_load_lds(
        (const __attribute__((address_space(1))) void*)(srcB + i),
        (__attribute__((address_space(3))) void*)(&sB[0][i]), 16, 0, 0);
  __syncthreads();

  f32x16 acc0 = {}, acc1 = {}, acc2 = {}, acc3 = {};
  const ushort* aw0 = packW + ((long)(z * 16 + 0 + w) * 96) * 512 + l * 8;
  const ushort* aw1 = packW + ((long)(z * 16 + 4 + w) * 96) * 512 + l * 8;
  const ushort* aw2 = packW + ((long)(z * 16 + 8 + w) * 96) * 512 + l * 8;
  const ushort* aw3 = packW + ((long)(z * 16 + 12 + w) * 96) * 512 + l * 8;

  int cur = 0;
  for (int ch = 0; ch < 8; ++ch) {
    if (ch + 1 < 8) {
      const ushort* src = srcB + (ch + 1) * 12 * 512;
      for (int i = tid * 8; i < 12 * 512; i += 2048)
        __builtin_amdgcn_global_load_lds(
            (const __attribute__((address_space(1))) void*)(src + i),
            (__attribute__((address_space(3))) void*)(&sB[cur ^ 1][i]), 16, 0, 0);
    }
    #pragma unroll
    for (int kcl = 0; kcl < 12; ++kcl) {
      const int kc = ch * 12 + kcl;
      bf16x8 bf = *reinterpret_cast<const bf16x8*>(&sB[cur][kcl * 512 + l * 8]);
      bf16x8 a0 = *reinterpret_cast<const bf16x8*>(aw0 + (long)kc * 512);
      acc0 = __builtin_amdgcn_mfma_f32_32x32x16_bf16(a0, bf, acc0, 0, 0, 0);
      bf16x8 a1 = *reinterpret_cast<const bf16x8*>(aw1 + (long)kc * 512);
      acc1 = __builtin_amdgcn_mfma_f32_32x32x16_bf16(a1, bf, acc1, 0, 0, 0);
      bf16x8 a2 = *reinterpret_cast<const bf16x8*>(aw2 + (long)kc * 512);
      acc2 = __builtin_amdgcn_mfma_f32_32x32x16_bf16(a2, bf, acc2, 0, 0, 0);
      bf16x8 a3 = *reinterpret_cast<const bf16x8*>(aw3 + (long)kc * 512);
      acc3 = __builtin_amdgcn_mfma_f32_32x32x16_bf16(a3, bf, acc3, 0, 0, 0);
    }
    __syncthreads();
    cur ^= 1;
  }

  FUS_EPI(acc0, 0)
  FUS_EPI(acc1, 1)
  FUS_EPI(acc2, 2)
  FUS_EPI(acc3, 3)
}

// --------------- BN stats from bf16 h sweep (one wave per (b,o)) ------------
__global__ __launch_bounds__(256) void stats_bf16(const ushort* __restrict__ hbf,
                                                  float* __restrict__ ps1,
                                                  float* __restrict__ ps2) {
  int gw = (blockIdx.x * 256 + threadIdx.x) >> 6;
  int lane = threadIdx.x & 63;
  int b = gw >> 10, o = gw & 1023;
  const ushort* row = hbf + ((long)b * 1024 + o) * 4096;
  float s1 = 0.f, s2 = 0.f;
  for (int j = 0; j < 8; ++j) {
    union { ushort u[8]; short8v v; } hv;
    hv.v = *reinterpret_cast<const short8v*>(row + ((j << 6) + lane) * 8);
    #pragma unroll
    for (int e = 0; e < 8; ++e) {
      float h = __uint_as_float((unsigned)hv.u[e] << 16);
      s1 += h;
      s2 = fmaf(h, h, s2);
    }
  }
  #pragma unroll
  for (int off = 1; off < 64; off <<= 1) {
    s1 += __shfl_xor(s1, off);
    s2 += __shfl_xor(s2, off);
  }
  if (lane == 0) {
    ps1[(long)b * 1024 + o] = s1;
    ps2[(long)b * 1024 + o] = s2;
  }
}

__global__ void finalize_fusion2(const float* __restrict__ ps1, const float* __restrict__ ps2,
                                 const float* __restrict__ g, const float* __restrict__ beta,
                                 float* __restrict__ scale, float* __restrict__ shift) {
  int o = blockIdx.x * 256 + threadIdx.x;
  if (o < 1024) {
    double s1 = 0.0, s2 = 0.0;
    for (int b = 0; b < 8; ++b) {
      s1 += (double)ps1[(long)b * 1024 + o];
      s2 += (double)ps2[(long)b * 1024 + o];
    }
    double invM = 1.0 / 32768.0;
    double mean = s1 * invM;
    double var = s2 * invM - mean * mean;
    double sc = (double)g[o] / sqrt(var + 1e-5);
    scale[o] = (float)sc;
    shift[o] = (float)((double)beta[o] - mean * sc);
  }
}

// --- pool: max from sign-flipped f32 partials, mean from bf16 sweep ---------
__global__ __launch_bounds__(256) void pool_v3(const ushort* __restrict__ hbf,
                                               const float* __restrict__ p3,
                                               const float* __restrict__ scale,
                                               const float* __restrict__ shift,
                                               float* __restrict__ x1x2) {
  int gw = (blockIdx.x * 256 + threadIdx.x) >> 6;
  int lane = threadIdx.x & 63;
  int b = gw >> 10, o = gw & 1023;
  float sc = scale[o], sh = shift[o];

  long pb = (long)o * 1024 + b * 128;
  float red = fmaxf(p3[pb + lane], p3[pb + 64 + lane]);
  #pragma unroll
  for (int off = 1; off < 64; off <<= 1) red = fmaxf(red, __shfl_xor(red, off));
  float hm = (sc >= 0.f) ? red : -red;
  float x1 = LEAKY(fmaf(sc, hm, sh));

  const ushort* row = hbf + ((long)b * 1024 + o) * 4096;
  float sm = 0.f;
  for (int j = 0; j < 8; ++j) {
    union { ushort u[8]; short8v v; } hv;
    hv.v = *reinterpret_cast<const short8v*>(row + ((j << 6) + lane) * 8);
    #pragma unroll
    for (int e = 0; e < 8; ++e) {
      float h = __uint_as_float((unsigned)hv.u[e] << 16);
      float y = fmaf(sc, h, sh);
      sm += LEAKY(y);
    }
  }
  #pragma unroll
  for (int off = 1; off < 64; off <<= 1) sm += __shfl_xor(sm, off);

  if (lane == 0) {
    x1x2[(long)b * 2048 + o] = x1;
    x1x2[(long)b * 2048 + 1024 + o] = sm * (1.f / 4096.f);
  }
}

// ----------------------------------------------------------- classifier -----
__global__ __launch_bounds__(256) void fc_kernel(const float* __restrict__ in, int Cin, int O,
                                                 const float* __restrict__ W,
                                                 const float* __restrict__ bias,
                                                 const float* __restrict__ g,
                                                 const float* __restrict__ beta,
                                                 float* __restrict__ outp, int do_bn) {
  const int tid = threadIdx.x;
  const int o = blockIdx.x * 32 + (tid >> 3);
  const int bb = tid & 7;
  const int oc = (o < O) ? o : (O - 1);
  const float* ir = in + (long)bb * Cin;
  const float* wr = W + (long)oc * Cin;
  float dot = 0.f;
  for (int c = 0; c < Cin; c += 4) {
    float4 a = *reinterpret_cast<const float4*>(&ir[c]);
    float4 w = *reinterpret_cast<const float4*>(&wr[c]);
    dot += a.x * w.x + a.y * w.y + a.z * w.z + a.w * w.w;
  }
  float h = dot + bias[oc];
  if (do_bn) {
    float s = h;
    s += __shfl_xor(s, 1, 8); s += __shfl_xor(s, 2, 8); s += __shfl_xor(s, 4, 8);
    float mean = s * 0.125f;
    float dv = (h - mean) * (h - mean);
    dv += __shfl_xor(dv, 1, 8); dv += __shfl_xor(dv, 2, 8); dv += __shfl_xor(dv, 4, 8);
    float var = dv * 0.125f;
    float y = (h - mean) * (float)(1.0 / sqrt((double)var + 1e-5)) * g[oc] + beta[oc];
    h = LEAKY(y);
  }
  if (o < O) outp[(long)bb * O + o] = h;
}

// ------------------------------------------------------- edge layer driver --
template<int Cin, int O>
static void edge_layer(const float* g, const float* beta,
                       float* featOut, long out_bstride,
                       const ushort* packX6, const ushort* packAwL,
                       float* u, float* v,
                       const int* idx, float* hsel, float* part1, float* part2,
                       float* scale, float* shift, int N, int B,
                       hipStream_t stream) {
  constexpr int KCW = (6 * Cin + 15) / 16;
  constexpr int NOB = O / 32;
  edge_gemm6<KCW, NOB><<<dim3(N / 32, B), 256, 0, stream>>>(packX6, packAwL, N, u, v);
  edge_pass<<<dim3(N / 64, O / 64, B), 256, 0, stream>>>(u, v, idx, g, O, N, hsel, part1, part2);
  finalize_scale<<<(O * 64 + 255) / 256, 256, 0, stream>>>(part1, part2, g, beta,
                                                           1.0 / ((double)B * N * 9), O,
                                                           scale, shift);
  edge_out<<<dim3(N / 64, B), 256, 0, stream>>>(hsel, scale, shift, O, N, featOut, out_bstride);
}

// ---------------------------------------------------------------- driver ----
extern "C" void kernel_launch(void* const* d_in, const int* in_sizes, int n_in,
                              void* d_out, int out_size, void* d_ws, size_t ws_size,
                              hipStream_t stream) {
  const int B = 8, N = 4096;
  const float* x   = (const float*)d_in[0];
  const float* w1 = (const float*)d_in[2];  const float* g1 = (const float*)d_in[3];  const float* b1 = (const float*)d_in[4];
  const float* w2 = (const float*)d_in[5];  const float* g2 = (const float*)d_in[6];  const float* b2 = (const float*)d_in[7];
  const float* w3 = (const float*)d_in[8];  const float* g3 = (const float*)d_in[9];  const float* b3 = (const float*)d_in[10];
  const float* w4 = (const float*)d_in[11]; const float* g4 = (const float*)d_in[12]; const float* b4 = (const float*)d_in[13];
  const float* wf = (const float*)d_in[14]; const float* bfv = (const float*)d_in[15];
  const float* gf = (const float*)d_in[16]; const float* betaf = (const float*)d_in[17];
  const float* wc1 = (const float*)d_in[18]; const float* bc1 = (const float*)d_in[19];
  const float* gc1 = (const float*)d_in[20]; const float* betac1 = (const float*)d_in[21];
  const float* wc2 = (const float*)d_in[22]; const float* bc2 = (const float*)d_in[23];
  const float* gc2 = (const float*)d_in[24]; const float* betac2 = (const float*)d_in[25];
  const float* wc3 = (const float*)d_in[26]; const float* bc3 = (const float*)d_in[27];

  char* p = (char*)d_ws;
  auto alloc = [&](size_t bytes) -> char* {
    char* r = p;
    p += (bytes + 255) & ~(size_t)255;
    return r;
  };
  float* feat  = (float*)alloc((size_t)B * 512 * N * 4);
  int*   idx   = (int*)  alloc((size_t)B * N * 9 * 4);
  int*   cand  = (int*)  alloc((size_t)B * N * 64 * 4);
  float* xxg   = (float*)alloc((size_t)B * N * 4);
  float* u     = (float*)alloc((size_t)B * N * 256 * 4);
  float* v     = (float*)alloc((size_t)B * N * 256 * 4);
  float* hmax  = (float*)alloc((size_t)B * N * 256 * 4);
  float* hmin  = (float*)alloc((size_t)B * N * 256 * 4);
  ushort* packR = (ushort*)u;
  ushort* packC = (ushort*)v;
  ushort* packX6 = (ushort*)hmax;
  float*  xpm   = (float*)((char*)hmin + 16777216);
  float*  hsel  = hmax;
  float*  part1 = hmin;
  float*  part2 = hmin + 131072;
  ushort* packB = (ushort*)u;
  ushort* hbf   = (ushort*)feat;
  float*  ps1   = hmin;
  float*  ps2   = hmin + 1048576;
  float*  ps3   = hmin + 2 * 1048576;
  ushort* packAw = (ushort*)alloc((size_t)544768 * 2);
  ushort* packW = (ushort*)alloc((size_t)32 * 96 * 512 * 2);
  float* scale = (float*)alloc(1024 * 4);
  float* shift = (float*)alloc(1024 * 4);
  float* x1x2  = (float*)alloc((size_t)B * 2048 * 4);
  float* h1    = (float*)alloc((size_t)B * 512 * 4);
  float* h2    = (float*)alloc((size_t)B * 256 * 4);

  const ushort* pawL1 = packAw;
  const ushort* pawL2 = packAw + 4096;
  const ushort* pawL3 = packAw + 53248;
  const ushort* pawL4 = packAw + 151552;

  dim3 gpack(N / 32, B);
  dim3 gknn4(N / 128, B, 4);
  dim3 gknn2(N / 128, B, 2);
  dim3 grr40(N / 8, B);
  dim3 grr20(N / 16, B);

  pack3_wf<<<32, 256, 0, stream>>>(wf, packW);
  pack6_w_all<<<32, 256, 0, stream>>>(w1, w2, w3, w4, packAw);

  // layer 1: C=3 (KCc=1, KCX=2)
  pack_layer<3, 1, 2><<<gpack, 256, 0, stream>>>(x, (long)3 * N, N, xxg,
                                                 packR, packC, xpm, packX6);
  knn_v5<1, 4, 4><<<gknn4, 256, 0, stream>>>(packR, packC, xxg, N, cand);
  rerank_kernel<3, 40><<<grr40, 320, 0, stream>>>(xpm, N, xxg, cand, idx);
  edge_layer<3, 64>(g1, b1, feat, (long)512 * N, packX6, pawL1, u, v, idx,
                    hsel, part1, part2, scale, shift, N, B, stream);

  // layer 2: C=64 (KCc=13, KCX=24)
  pack_layer<64, 13, 24><<<gpack, 256, 0, stream>>>(feat, (long)512 * N, N, xxg,
                                                    packR, packC, xpm, packX6);
  knn_v5<13, 3, 4><<<gknn4, 256, 0, stream>>>(packR, packC, xxg, N, cand);
  rerank_kernel<64, 40><<<grr40, 320, 0, stream>>>(xpm, N, xxg, cand, idx);
  edge_layer<64, 64>(g2, b2, feat + (long)64 * N, (long)512 * N, packX6, pawL2,
                     u, v, idx, hsel, part1, part2, scale, shift, N, B, stream);

  // layer 3: C=64
  pack_layer<64, 13, 24><<<gpack, 256, 0, stream>>>(feat + (long)64 * N, (long)512 * N, N, xxg,
                                                    packR, packC, xpm, packX6);
  knn_v5<13, 3, 4><<<gknn4, 256, 0, stream>>>(packR, packC, xxg, N, cand);
  rerank_kernel<64, 40><<<grr40, 320, 0, stream>>>(xpm, N, xxg, cand, idx);
  edge_layer<64, 128>(g3, b3, feat + (long)128 * N, (long)512 * N, packX6, pawL3,
                      u, v, idx, hsel, part1, part2, scale, shift, N, B, stream);

  // layer 4: C=128 (KCc=25, KCX=48; z=2, pool 20 — measured best)
  pack_layer<128, 25, 48><<<gpack, 256, 0, stream>>>(feat + (long)128 * N, (long)512 * N, N, xxg,
                                                     packR, packC, xpm, packX6);
  knn_v5<25, 3, 2><<<gknn2, 256, 0, stream>>>(packR, packC, xxg, N, cand);
  rerank_kernel<128, 20><<<grr20, 320, 0, stream>>>(xpm, N, xxg, cand, idx);
  edge_layer<128, 256>(g4, b4, feat + (long)256 * N, (long)512 * N, packX6, pawL4,
                       u, v, idx, hsel, part1, part2, scale, shift, N, B, stream);

  // fusion conv 512->1024 (z=2, 4 accs/wave)
  pack3_feat<<<dim3(N / 32, B), 256, 0, stream>>>(feat, N, packB);
  dim3 gfu(N / 32, 2, B);
  fusion_gemm_store<<<gfu, 256, 0, stream>>>(packW, packB, bfv, gf, N, hbf, ps3);
  stats_bf16<<<2048, 256, 0, stream>>>(hbf, ps1, ps2);
  finalize_fusion2<<<4, 256, 0, stream>>>(ps1, ps2, gf, betaf, scale, shift);
  pool_v3<<<2048, 256, 0, stream>>>(hbf, ps3, scale, shift, x1x2);

  fc_kernel<<<16, 256, 0, stream>>>(x1x2, 2048, 512, wc1, bc1, gc1, betac1, h1, 1);
  fc_kernel<<<8, 256, 0, stream>>>(h1, 512, 256, wc2, bc2, gc2, betac2, h2, 1);
  fc_kernel<<<2, 256, 0, stream>>>(h2, 256, 40, wc3, bc3, nullptr, nullptr, (float*)d_out, 0);
}